// Round 2
// baseline (373.197 us; speedup 1.0000x reference)
//
#include <hip/hip_runtime.h>
#include <hip/hip_fp16.h>

#define N_POINTS 500000
#define BN_EPS 1e-5f
#define A_COEF -0.75f

typedef __attribute__((ext_vector_type(8))) short short8;
typedef __attribute__((ext_vector_type(4))) float floatx4;
typedef __attribute__((ext_vector_type(8))) _Float16 half8;
typedef unsigned short ushort_t;
typedef unsigned int uint_t;

// -------- workspace layout (float offsets) --------
#define WS_WBF_OFF    0                          // bf16 weights [tap(9)][oc(64)][ic(64)]   : 18432 floats
#define WS_CONV_OFF   18432                      // conv HWC fp32 [3][128][128][64]          : 3145728
#define WS_SUM_OFF    (WS_CONV_OFF + 3145728)    // [3][64]                                  : 192
#define WS_SUMSQ_OFF  (WS_SUM_OFF + 192)
#define WS_SCALE_OFF  (WS_SUMSQ_OFF + 192)
#define WS_SHIFT_OFF  (WS_SCALE_OFF + 192)
#define WS_PLANES_OFF (WS_SHIFT_OFF + 192)       // fp16 planes HWC [3][128][128][64]        : 1572864 floats
#define WS_INBF_OFF   (WS_PLANES_OFF + 1572864)  // bf16 input HWC [3][256][256][64]         : 6291456 floats
// total ~44.1 MB

__device__ __forceinline__ ushort_t f2bf(float f) {
  uint_t u = __float_as_uint(f);
  uint_t r = (u + 0x7fffu + ((u >> 16) & 1u)) >> 16;
  return (ushort_t)r;
}
__device__ __forceinline__ float bf2f(ushort_t u) {
  return __uint_as_float(((uint_t)u) << 16);
}

// ================= prep: weights [oc][ic][3][3] fp32 -> [tap][oc][ic] bf16; zero stat accums
__global__ __launch_bounds__(256) void wprep_kernel(const float* __restrict__ w_in,
                                                    float* __restrict__ ws) {
  int i = blockIdx.x * 256 + threadIdx.x;  // < 36864
  if (i < 36864) {
    int ic = i & 63;
    int oc = (i >> 6) & 63;
    int kk = i >> 12;  // 0..8
    ((ushort_t*)(ws + WS_WBF_OFF))[i] = f2bf(w_in[(oc * 64 + ic) * 9 + kk]);
  }
  if (i < 384) ws[WS_SUM_OFF + i] = 0.0f;  // sums + sumsq contiguous
}

// ================= transpose: input CHW fp32 -> HWC bf16
// grid (4, 256, 3): x-tile, row y, plane
__global__ __launch_bounds__(256) void transpose_kernel(const float* __restrict__ p0,
                                                        const float* __restrict__ p1,
                                                        const float* __restrict__ p2,
                                                        float* __restrict__ ws) {
  __shared__ float tile[64][65];
  const int xt = blockIdx.x, y = blockIdx.y, pl = blockIdx.z;
  const float* src = (pl == 0) ? p0 : ((pl == 1) ? p1 : p2);
  ushort_t* dst = (ushort_t*)(ws + WS_INBF_OFF) + pl * (256 * 256 * 64);
  const int t = threadIdx.x;
  const int x0 = xt * 64;
  for (int i = t; i < 4096; i += 256) {
    int c = i >> 6, x = i & 63;
    tile[x][c] = src[(c * 256 + y) * 256 + x0 + x];
  }
  __syncthreads();
  uint_t* du = (uint_t*)dst;
  for (int i = t; i < 2048; i += 256) {
    int x = i >> 5, cp = (i & 31) * 2;
    uint_t lo = f2bf(tile[x][cp]);
    uint_t hi = f2bf(tile[x][cp + 1]);
    du[((y * 256 + x0 + x) * 64 + cp) >> 1] = (hi << 16) | lo;
  }
}

// ================= conv3x3 stride2 pad1 via MFMA bf16 (bias dropped: cancels in batch-stat BN)
// grid (2, 128, 3). 4 waves; wave computes 16 px x 64 oc. A from global HWC bf16, B from bf16 weights.
__global__ __launch_bounds__(256) void conv_mfma_kernel(const float* __restrict__ ws_r,
                                                        float* __restrict__ ws) {
  const int xh = blockIdx.x, oy = blockIdx.y, pz = blockIdx.z;
  const int t = threadIdx.x;
  const int wv = t >> 6, lane = t & 63;
  const int mn = lane & 15;   // A: px row m ; B: oc col n
  const int kg = lane >> 4;   // k-group (k = kg*8 + j)
  const int x0w = xh * 64 + wv * 16;

  const ushort_t* inb = (const ushort_t*)(ws_r + WS_INBF_OFF) + pz * (256 * 256 * 64);
  const ushort_t* wbf = (const ushort_t*)(ws_r + WS_WBF_OFF);

  floatx4 acc[4] = {{0.f,0.f,0.f,0.f},{0.f,0.f,0.f,0.f},{0.f,0.f,0.f,0.f},{0.f,0.f,0.f,0.f}};

  for (int ky = 0; ky < 3; ky++) {
    int y = 2 * oy - 1 + ky;
    if (y < 0) continue;  // y <= 255 always
    const ushort_t* rowp = inb + y * (256 * 64);
    for (int kx = 0; kx < 3; kx++) {
      int xm = 2 * (x0w + mn) - 1 + kx;     // only -1 can be OOB (max 255)
      bool vx = xm >= 0;
      int xc = vx ? xm : 0;
      const ushort_t* abase = rowp + xc * 64 + kg * 8;
      const ushort_t* wbase = wbf + ((ky * 3 + kx) * 64 + mn) * 64 + kg * 8;
#pragma unroll
      for (int kc = 0; kc < 2; kc++) {
        union { int4 i4; short8 s8; } au;
        au.i4 = *reinterpret_cast<const int4*>(abase + kc * 32);
        if (!vx) au.i4 = make_int4(0, 0, 0, 0);
#pragma unroll
        for (int nt = 0; nt < 4; nt++) {
          union { int4 i4; short8 s8; } bu;
          bu.i4 = *reinterpret_cast<const int4*>(wbase + nt * 1024 + kc * 32);
          acc[nt] = __builtin_amdgcn_mfma_f32_16x16x32_bf16(au.s8, bu.s8, acc[nt], 0, 0, 0);
        }
      }
    }
  }
  // D: col(oc) = lane&15, row(px) = (lane>>4)*4 + reg
  float* cout = ws + WS_CONV_OFF + ((pz * 128 + oy) * 128 + x0w) * 64;
#pragma unroll
  for (int nt = 0; nt < 4; nt++) {
#pragma unroll
    for (int r = 0; r < 4; r++) {
      cout[(kg * 4 + r) * 64 + nt * 16 + mn] = acc[nt][r];
    }
  }
}

// ================= BN stats: per (plane, channel) sum & sumsq over 16384 px
__global__ __launch_bounds__(256) void stats_kernel(float* __restrict__ ws) {
  const int b = blockIdx.x;
  const int plane = b >> 6, chunk = b & 63;
  const int t = threadIdx.x;
  const int c = t & 63, g = t >> 6;
  const float* base = ws + WS_CONV_OFF + plane * (16384 * 64);
  float s = 0.0f, s2 = 0.0f;
  const int row0 = chunk * 256 + g * 64;
  for (int i = 0; i < 64; i++) {
    float v = base[(row0 + i) * 64 + c];
    s += v;
    s2 = fmaf(v, v, s2);
  }
  __shared__ float rs[256], rs2[256];
  rs[t] = s; rs2[t] = s2;
  __syncthreads();
  if (t < 64) {
    s = rs[t] + rs[t + 64] + rs[t + 128] + rs[t + 192];
    s2 = rs2[t] + rs2[t + 64] + rs2[t + 128] + rs2[t + 192];
    atomicAdd(&ws[WS_SUM_OFF + plane * 64 + c], s);
    atomicAdd(&ws[WS_SUMSQ_OFF + plane * 64 + c], s2);
  }
}

__global__ void finalize_kernel(const float* __restrict__ gamma,
                                const float* __restrict__ beta,
                                float* __restrict__ ws) {
  int i = threadIdx.x;
  if (i < 192) {
    int c = i & 63;
    float mu = ws[WS_SUM_OFF + i] * (1.0f / 16384.0f);
    float var = ws[WS_SUMSQ_OFF + i] * (1.0f / 16384.0f) - mu * mu;
    var = fmaxf(var, 0.0f);
    float rstd = 1.0f / sqrtf(var + BN_EPS);
    float sc = gamma[c] * rstd;
    ws[WS_SCALE_OFF + i] = sc;
    ws[WS_SHIFT_OFF + i] = beta[c] - mu * sc;
  }
}

// ================= apply BN + relu + fused avgpool(3x3 s2 p1, count_include_pad) + pack fp16
// thread = (plane, px, 8-channel group); 393216 threads
__global__ __launch_bounds__(256) void apply_kernel(float* __restrict__ ws,
                                                    __half* __restrict__ planes) {
  int idx = blockIdx.x * 256 + threadIdx.x;  // < 393216
  int g = idx & 7;
  int p = (idx >> 3) & 16383;
  int pl = idx >> 17;
  int oy = p >> 7, ox = p & 127;
  int cb = g * 8;

  const float* conv = ws + WS_CONV_OFF;
  float4 a0 = *reinterpret_cast<const float4*>(conv + (size_t)idx * 8);
  float4 a1 = *reinterpret_cast<const float4*>(conv + (size_t)idx * 8 + 4);

  float sc[8], sh[8];
#pragma unroll
  for (int k = 0; k < 8; k++) {
    sc[k] = ws[WS_SCALE_OFF + pl * 64 + cb + k];
    sh[k] = ws[WS_SHIFT_OFF + pl * 64 + cb + k];
  }

  const ushort_t* inb = (const ushort_t*)(ws + WS_INBF_OFF) + pl * (256 * 256 * 64);
  float ps[8];
#pragma unroll
  for (int k = 0; k < 8; k++) ps[k] = 0.0f;
#pragma unroll
  for (int r = 0; r < 3; r++) {
    int yy = 2 * oy - 1 + r;
    if (yy < 0) continue;  // <= 255 always
#pragma unroll
    for (int s = 0; s < 3; s++) {
      int xx = 2 * ox - 1 + s;
      if (xx < 0) continue;
      union { int4 i4; ushort_t u[8]; } ub;
      ub.i4 = *reinterpret_cast<const int4*>(inb + (yy * 256 + xx) * 64 + cb);
#pragma unroll
      for (int k = 0; k < 8; k++) ps[k] += bf2f(ub.u[k]);
    }
  }

  float v[8] = {a0.x, a0.y, a0.z, a0.w, a1.x, a1.y, a1.z, a1.w};
  union { int4 i4; __half h[8]; } ob;
#pragma unroll
  for (int k = 0; k < 8; k++) {
    float r = fmaxf(fmaf(v[k], sc[k], sh[k]), 0.0f) + ps[k] * (1.0f / 9.0f);
    ob.h[k] = __float2half(r);
  }
  *reinterpret_cast<int4*>(planes + (size_t)idx * 8) = ob.i4;
}

// ================= bicubic sampling, 3 planes fused
__device__ __forceinline__ void cubic_w(float t, float w[4]) {
  float t1 = t + 1.0f;
  w[0] = ((A_COEF * t1 - 5.0f * A_COEF) * t1 + 8.0f * A_COEF) * t1 - 4.0f * A_COEF;
  w[1] = ((A_COEF + 2.0f) * t - (A_COEF + 3.0f)) * t * t + 1.0f;
  float s = 1.0f - t;
  w[2] = ((A_COEF + 2.0f) * s - (A_COEF + 3.0f)) * s * s + 1.0f;
  w[3] = 1.0f - w[0] - w[1] - w[2];
}

// group of 8 lanes = one point; lane l handles channels [l*8, l*8+8).
// v2: 16-tap register preload per plane (MLP), v_fma_mix inner loop (no cvt),
//     32-bit voffset addressing, nontemporal stream loads/stores.
__global__ __launch_bounds__(256, 4) void sample_kernel(const float* __restrict__ coords,
                                                        const float* __restrict__ noise,
                                                        const __half* __restrict__ planes,
                                                        float* __restrict__ out) {
  const int t = threadIdx.x;
  const int wv = t >> 6, lane = t & 63;
  const int g = lane >> 3, l = lane & 7;
  const int n = blockIdx.x * 32 + wv * 8 + g;

  const float c0 = (__builtin_nontemporal_load(coords + n * 3 + 0) + 1.0f) * 0.5f;
  const float c1 = (__builtin_nontemporal_load(coords + n * 3 + 1) + 1.0f) * 0.5f;
  const float c2 = (__builtin_nontemporal_load(coords + n * 3 + 2) + 1.0f) * 0.5f;

  const _Float16* pbase = reinterpret_cast<const _Float16*>(planes) + l * 8;
  const float* nbase = noise + (size_t)n * 2;

  float acc[8];
#pragma unroll
  for (int e = 0; e < 8; e++) acc[e] = 0.0f;

#pragma unroll 1
  for (int p = 0; p < 3; p++) {
    float u = (p == 1) ? c1 : c0;   // p0:(c0,c1) p1:(c1,c2) p2:(c0,c2)
    float v = (p == 0) ? c1 : c2;
    u += __builtin_nontemporal_load(nbase + (size_t)p * (N_POINTS * 2) + 0);
    v += __builtin_nontemporal_load(nbase + (size_t)p * (N_POINTS * 2) + 1);
    float gx = fminf(fmaxf(fmaf(u, 63.5f, 63.5f), 0.0f), 127.0f);
    float gy = fminf(fmaxf(fmaf(v, 63.5f, 63.5f), 0.0f), 127.0f);
    float x0f = floorf(gx), y0f = floorf(gy);
    float tx = gx - x0f, ty = gy - y0f;
    int ix = (int)x0f, iy = (int)y0f;
    float wx[4], wy[4];
    cubic_w(tx, wx);
    cubic_w(ty, wy);

    // 32-bit element offsets into the fp16 plane array (uniform base + voffset)
    const _Float16* pb = pbase + p * (128 * 128 * 64);
    int ro[4], xo[4];
#pragma unroll
    for (int i = 0; i < 4; i++) ro[i] = min(max(iy - 1 + i, 0), 127) * (128 * 64);
#pragma unroll
    for (int j = 0; j < 4; j++) xo[j] = min(max(ix - 1 + j, 0), 127) * 64;

    // issue all 16 tap loads before consuming any (16 outstanding dwordx4)
    half8 ub[16];
#pragma unroll
    for (int i = 0; i < 4; i++) {
#pragma unroll
      for (int j = 0; j < 4; j++) {
        ub[i * 4 + j] = *reinterpret_cast<const half8*>(pb + ro[i] + xo[j]);
      }
    }

    // consume: fma(fpext(f16), f32, f32) -> v_fma_mix_f32 (no separate cvt)
#pragma unroll
    for (int i = 0; i < 4; i++) {
#pragma unroll
      for (int j = 0; j < 4; j++) {
        float w = wy[i] * wx[j];
        half8 hv = ub[i * 4 + j];
#pragma unroll
        for (int q = 0; q < 8; q++) {
          acc[q] = fmaf((float)hv[q], w, acc[q]);
        }
      }
    }
  }

  float* op = out + (size_t)n * 64 + l * 8;
  floatx4 o0 = {acc[0], acc[1], acc[2], acc[3]};
  floatx4 o1 = {acc[4], acc[5], acc[6], acc[7]};
  __builtin_nontemporal_store(o0, reinterpret_cast<floatx4*>(op));
  __builtin_nontemporal_store(o1, reinterpret_cast<floatx4*>(op + 4));
}

extern "C" void kernel_launch(void* const* d_in, const int* in_sizes, int n_in,
                              void* d_out, int out_size, void* d_ws, size_t ws_size,
                              hipStream_t stream) {
  const float* coords = (const float*)d_in[0];
  const float* noise  = (const float*)d_in[1];
  const float* px     = (const float*)d_in[2];
  const float* py     = (const float*)d_in[3];
  const float* pz     = (const float*)d_in[4];
  const float* conv_w = (const float*)d_in[5];
  // conv_b (d_in[6]) unused: bias cancels exactly under batch-stat BN
  const float* gamma  = (const float*)d_in[7];
  const float* beta   = (const float*)d_in[8];
  float* out = (float*)d_out;
  float* ws = (float*)d_ws;
  __half* planes = (__half*)(ws + WS_PLANES_OFF);

  wprep_kernel<<<144, 256, 0, stream>>>(conv_w, ws);
  transpose_kernel<<<dim3(4, 256, 3), 256, 0, stream>>>(px, py, pz, ws);
  conv_mfma_kernel<<<dim3(2, 128, 3), 256, 0, stream>>>(ws, ws);
  stats_kernel<<<192, 256, 0, stream>>>(ws);
  finalize_kernel<<<1, 256, 0, stream>>>(gamma, beta, ws);
  apply_kernel<<<1536, 256, 0, stream>>>(ws, planes);
  sample_kernel<<<15625, 256, 0, stream>>>(coords, noise, planes, out);
}

// Round 3
// 368.167 us; speedup vs baseline: 1.0137x; 1.0137x over previous
//
#include <hip/hip_runtime.h>
#include <hip/hip_fp16.h>

#define N_POINTS 500000
#define BN_EPS 1e-5f
#define A_COEF -0.75f

typedef __attribute__((ext_vector_type(8))) short short8;
typedef __attribute__((ext_vector_type(4))) float floatx4;
typedef unsigned short ushort_t;
typedef unsigned int uint_t;

// -------- workspace layout (float offsets) --------
#define WS_WBF_OFF    0                          // bf16 weights [tap(9)][oc(64)][ic(64)]   : 18432 floats
#define WS_CONV_OFF   18432                      // conv HWC fp32 [3][128][128][64]          : 3145728
#define WS_SUM_OFF    (WS_CONV_OFF + 3145728)    // [3][64]                                  : 192
#define WS_SUMSQ_OFF  (WS_SUM_OFF + 192)
#define WS_SCALE_OFF  (WS_SUMSQ_OFF + 192)
#define WS_SHIFT_OFF  (WS_SCALE_OFF + 192)
#define WS_PLANES_OFF (WS_SHIFT_OFF + 192)       // fp16 planes HWC [3][128][128][64]        : 1572864 floats
#define WS_INBF_OFF   (WS_PLANES_OFF + 1572864)  // bf16 input HWC [3][256][256][64]         : 6291456 floats
// total ~44.1 MB

__device__ __forceinline__ ushort_t f2bf(float f) {
  uint_t u = __float_as_uint(f);
  uint_t r = (u + 0x7fffu + ((u >> 16) & 1u)) >> 16;
  return (ushort_t)r;
}
__device__ __forceinline__ float bf2f(ushort_t u) {
  return __uint_as_float(((uint_t)u) << 16);
}

// ================= prep: weights [oc][ic][3][3] fp32 -> [tap][oc][ic] bf16; zero stat accums
__global__ __launch_bounds__(256) void wprep_kernel(const float* __restrict__ w_in,
                                                    float* __restrict__ ws) {
  int i = blockIdx.x * 256 + threadIdx.x;  // < 36864
  if (i < 36864) {
    int ic = i & 63;
    int oc = (i >> 6) & 63;
    int kk = i >> 12;  // 0..8
    ((ushort_t*)(ws + WS_WBF_OFF))[i] = f2bf(w_in[(oc * 64 + ic) * 9 + kk]);
  }
  if (i < 384) ws[WS_SUM_OFF + i] = 0.0f;  // sums + sumsq contiguous
}

// ================= transpose: input CHW fp32 -> HWC bf16
// grid (4, 256, 3): x-tile, row y, plane
__global__ __launch_bounds__(256) void transpose_kernel(const float* __restrict__ p0,
                                                        const float* __restrict__ p1,
                                                        const float* __restrict__ p2,
                                                        float* __restrict__ ws) {
  __shared__ float tile[64][65];
  const int xt = blockIdx.x, y = blockIdx.y, pl = blockIdx.z;
  const float* src = (pl == 0) ? p0 : ((pl == 1) ? p1 : p2);
  ushort_t* dst = (ushort_t*)(ws + WS_INBF_OFF) + pl * (256 * 256 * 64);
  const int t = threadIdx.x;
  const int x0 = xt * 64;
  for (int i = t; i < 4096; i += 256) {
    int c = i >> 6, x = i & 63;
    tile[x][c] = src[(c * 256 + y) * 256 + x0 + x];
  }
  __syncthreads();
  uint_t* du = (uint_t*)dst;
  for (int i = t; i < 2048; i += 256) {
    int x = i >> 5, cp = (i & 31) * 2;
    uint_t lo = f2bf(tile[x][cp]);
    uint_t hi = f2bf(tile[x][cp + 1]);
    du[((y * 256 + x0 + x) * 64 + cp) >> 1] = (hi << 16) | lo;
  }
}

// ================= conv3x3 stride2 pad1 via MFMA bf16 (bias dropped: cancels in batch-stat BN)
// grid (2, 128, 3). 4 waves; wave computes 16 px x 64 oc. A from global HWC bf16, B from bf16 weights.
__global__ __launch_bounds__(256) void conv_mfma_kernel(const float* __restrict__ ws_r,
                                                        float* __restrict__ ws) {
  const int xh = blockIdx.x, oy = blockIdx.y, pz = blockIdx.z;
  const int t = threadIdx.x;
  const int wv = t >> 6, lane = t & 63;
  const int mn = lane & 15;   // A: px row m ; B: oc col n
  const int kg = lane >> 4;   // k-group (k = kg*8 + j)
  const int x0w = xh * 64 + wv * 16;

  const ushort_t* inb = (const ushort_t*)(ws_r + WS_INBF_OFF) + pz * (256 * 256 * 64);
  const ushort_t* wbf = (const ushort_t*)(ws_r + WS_WBF_OFF);

  floatx4 acc[4] = {{0.f,0.f,0.f,0.f},{0.f,0.f,0.f,0.f},{0.f,0.f,0.f,0.f},{0.f,0.f,0.f,0.f}};

  for (int ky = 0; ky < 3; ky++) {
    int y = 2 * oy - 1 + ky;
    if (y < 0) continue;  // y <= 255 always
    const ushort_t* rowp = inb + y * (256 * 64);
    for (int kx = 0; kx < 3; kx++) {
      int xm = 2 * (x0w + mn) - 1 + kx;     // only -1 can be OOB (max 255)
      bool vx = xm >= 0;
      int xc = vx ? xm : 0;
      const ushort_t* abase = rowp + xc * 64 + kg * 8;
      const ushort_t* wbase = wbf + ((ky * 3 + kx) * 64 + mn) * 64 + kg * 8;
#pragma unroll
      for (int kc = 0; kc < 2; kc++) {
        union { int4 i4; short8 s8; } au;
        au.i4 = *reinterpret_cast<const int4*>(abase + kc * 32);
        if (!vx) au.i4 = make_int4(0, 0, 0, 0);
#pragma unroll
        for (int nt = 0; nt < 4; nt++) {
          union { int4 i4; short8 s8; } bu;
          bu.i4 = *reinterpret_cast<const int4*>(wbase + nt * 1024 + kc * 32);
          acc[nt] = __builtin_amdgcn_mfma_f32_16x16x32_bf16(au.s8, bu.s8, acc[nt], 0, 0, 0);
        }
      }
    }
  }
  // D: col(oc) = lane&15, row(px) = (lane>>4)*4 + reg
  float* cout = ws + WS_CONV_OFF + ((pz * 128 + oy) * 128 + x0w) * 64;
#pragma unroll
  for (int nt = 0; nt < 4; nt++) {
#pragma unroll
    for (int r = 0; r < 4; r++) {
      cout[(kg * 4 + r) * 64 + nt * 16 + mn] = acc[nt][r];
    }
  }
}

// ================= BN stats: per (plane, channel) sum & sumsq over 16384 px
__global__ __launch_bounds__(256) void stats_kernel(float* __restrict__ ws) {
  const int b = blockIdx.x;
  const int plane = b >> 6, chunk = b & 63;
  const int t = threadIdx.x;
  const int c = t & 63, g = t >> 6;
  const float* base = ws + WS_CONV_OFF + plane * (16384 * 64);
  float s = 0.0f, s2 = 0.0f;
  const int row0 = chunk * 256 + g * 64;
  for (int i = 0; i < 64; i++) {
    float v = base[(row0 + i) * 64 + c];
    s += v;
    s2 = fmaf(v, v, s2);
  }
  __shared__ float rs[256], rs2[256];
  rs[t] = s; rs2[t] = s2;
  __syncthreads();
  if (t < 64) {
    s = rs[t] + rs[t + 64] + rs[t + 128] + rs[t + 192];
    s2 = rs2[t] + rs2[t + 64] + rs2[t + 128] + rs2[t + 192];
    atomicAdd(&ws[WS_SUM_OFF + plane * 64 + c], s);
    atomicAdd(&ws[WS_SUMSQ_OFF + plane * 64 + c], s2);
  }
}

__global__ void finalize_kernel(const float* __restrict__ gamma,
                                const float* __restrict__ beta,
                                float* __restrict__ ws) {
  int i = threadIdx.x;
  if (i < 192) {
    int c = i & 63;
    float mu = ws[WS_SUM_OFF + i] * (1.0f / 16384.0f);
    float var = ws[WS_SUMSQ_OFF + i] * (1.0f / 16384.0f) - mu * mu;
    var = fmaxf(var, 0.0f);
    float rstd = 1.0f / sqrtf(var + BN_EPS);
    float sc = gamma[c] * rstd;
    ws[WS_SCALE_OFF + i] = sc;
    ws[WS_SHIFT_OFF + i] = beta[c] - mu * sc;
  }
}

// ================= apply BN + relu + fused avgpool(3x3 s2 p1, count_include_pad) + pack fp16
// thread = (plane, px, 8-channel group); 393216 threads
__global__ __launch_bounds__(256) void apply_kernel(float* __restrict__ ws,
                                                    __half* __restrict__ planes) {
  int idx = blockIdx.x * 256 + threadIdx.x;  // < 393216
  int g = idx & 7;
  int p = (idx >> 3) & 16383;
  int pl = idx >> 17;
  int oy = p >> 7, ox = p & 127;
  int cb = g * 8;

  const float* conv = ws + WS_CONV_OFF;
  float4 a0 = *reinterpret_cast<const float4*>(conv + (size_t)idx * 8);
  float4 a1 = *reinterpret_cast<const float4*>(conv + (size_t)idx * 8 + 4);

  float sc[8], sh[8];
#pragma unroll
  for (int k = 0; k < 8; k++) {
    sc[k] = ws[WS_SCALE_OFF + pl * 64 + cb + k];
    sh[k] = ws[WS_SHIFT_OFF + pl * 64 + cb + k];
  }

  const ushort_t* inb = (const ushort_t*)(ws + WS_INBF_OFF) + pl * (256 * 256 * 64);
  float ps[8];
#pragma unroll
  for (int k = 0; k < 8; k++) ps[k] = 0.0f;
#pragma unroll
  for (int r = 0; r < 3; r++) {
    int yy = 2 * oy - 1 + r;
    if (yy < 0) continue;  // <= 255 always
#pragma unroll
    for (int s = 0; s < 3; s++) {
      int xx = 2 * ox - 1 + s;
      if (xx < 0) continue;
      union { int4 i4; ushort_t u[8]; } ub;
      ub.i4 = *reinterpret_cast<const int4*>(inb + (yy * 256 + xx) * 64 + cb);
#pragma unroll
      for (int k = 0; k < 8; k++) ps[k] += bf2f(ub.u[k]);
    }
  }

  float v[8] = {a0.x, a0.y, a0.z, a0.w, a1.x, a1.y, a1.z, a1.w};
  union { int4 i4; __half h[8]; } ob;
#pragma unroll
  for (int k = 0; k < 8; k++) {
    float r = fmaxf(fmaf(v[k], sc[k], sh[k]), 0.0f) + ps[k] * (1.0f / 9.0f);
    ob.h[k] = __float2half(r);
  }
  *reinterpret_cast<int4*>(planes + (size_t)idx * 8) = ob.i4;
}

// ================= bicubic sampling, 3 planes fused
__device__ __forceinline__ void cubic_w(float t, float w[4]) {
  float t1 = t + 1.0f;
  w[0] = ((A_COEF * t1 - 5.0f * A_COEF) * t1 + 8.0f * A_COEF) * t1 - 4.0f * A_COEF;
  w[1] = ((A_COEF + 2.0f) * t - (A_COEF + 3.0f)) * t * t + 1.0f;
  float s = 1.0f - t;
  w[2] = ((A_COEF + 2.0f) * s - (A_COEF + 3.0f)) * s * s + 1.0f;
  w[3] = 1.0f - w[0] - w[1] - w[2];
}

// v_fma_mix_f32: acc += fpext(f16 half of d) * w. Exact fpext+fma-f32 (same
// numerics as cvt+fmaf), 1 VALU op per channel instead of 2-3.
__device__ __forceinline__ void fma_mix_pair(float& alo, float& ahi, uint_t d, float w) {
  asm("v_fma_mix_f32 %0, %1, %2, %0 op_sel:[0,0,0] op_sel_hi:[1,0,0]"
      : "+v"(alo) : "v"(d), "v"(w));
  asm("v_fma_mix_f32 %0, %1, %2, %0 op_sel:[1,0,0] op_sel_hi:[1,0,0]"
      : "+v"(ahi) : "v"(d), "v"(w));
}

// group of 8 lanes = one point; lane l handles channels [l*8, l*8+8).
// v3: inline-asm v_fma_mix inner loop (8 VALU/tap guaranteed), full 3-plane
//     unroll restored (cross-plane load/compute overlap), plain loads/stores.
__global__ __launch_bounds__(256) void sample_kernel(const float* __restrict__ coords,
                                                     const float* __restrict__ noise,
                                                     const __half* __restrict__ planes,
                                                     float* __restrict__ out) {
  const int t = threadIdx.x;
  const int wv = t >> 6, lane = t & 63;
  const int g = lane >> 3, l = lane & 7;
  const int n = blockIdx.x * 32 + wv * 8 + g;

  const float c0 = (coords[n * 3 + 0] + 1.0f) * 0.5f;
  const float c1 = (coords[n * 3 + 1] + 1.0f) * 0.5f;
  const float c2 = (coords[n * 3 + 2] + 1.0f) * 0.5f;

  const __half* pbase = planes + l * 8;

  float acc[8];
#pragma unroll
  for (int e = 0; e < 8; e++) acc[e] = 0.0f;

#pragma unroll
  for (int p = 0; p < 3; p++) {
    float u = (p == 1) ? c1 : c0;   // p0:(c0,c1) p1:(c1,c2) p2:(c0,c2)
    float v = (p == 0) ? c1 : c2;
    u += noise[(p * N_POINTS + n) * 2 + 0];
    v += noise[(p * N_POINTS + n) * 2 + 1];
    float gx = fminf(fmaxf(fmaf(u, 63.5f, 63.5f), 0.0f), 127.0f);
    float gy = fminf(fmaxf(fmaf(v, 63.5f, 63.5f), 0.0f), 127.0f);
    float x0f = floorf(gx), y0f = floorf(gy);
    float tx = gx - x0f, ty = gy - y0f;
    int ix = (int)x0f, iy = (int)y0f;
    float wx[4], wy[4];
    cubic_w(tx, wx);
    cubic_w(ty, wy);

    const __half* pb = pbase + p * (128 * 128 * 64);
    int ro[4], xo[4];
#pragma unroll
    for (int i = 0; i < 4; i++) ro[i] = min(max(iy - 1 + i, 0), 127) * (128 * 64);
#pragma unroll
    for (int j = 0; j < 4; j++) xo[j] = min(max(ix - 1 + j, 0), 127) * 64;

    // 16 taps, static-indexed; compiler schedules loads ahead of the mix chain
    uint4 q[16];
#pragma unroll
    for (int i = 0; i < 4; i++) {
#pragma unroll
      for (int j = 0; j < 4; j++) {
        q[i * 4 + j] = *reinterpret_cast<const uint4*>(pb + ro[i] + xo[j]);
      }
    }
#pragma unroll
    for (int i = 0; i < 4; i++) {
#pragma unroll
      for (int j = 0; j < 4; j++) {
        float w = wy[i] * wx[j];
        uint4 d = q[i * 4 + j];
        fma_mix_pair(acc[0], acc[1], d.x, w);
        fma_mix_pair(acc[2], acc[3], d.y, w);
        fma_mix_pair(acc[4], acc[5], d.z, w);
        fma_mix_pair(acc[6], acc[7], d.w, w);
      }
    }
  }

  float* op = out + (size_t)n * 64 + l * 8;
  *reinterpret_cast<float4*>(op)     = make_float4(acc[0], acc[1], acc[2], acc[3]);
  *reinterpret_cast<float4*>(op + 4) = make_float4(acc[4], acc[5], acc[6], acc[7]);
}

extern "C" void kernel_launch(void* const* d_in, const int* in_sizes, int n_in,
                              void* d_out, int out_size, void* d_ws, size_t ws_size,
                              hipStream_t stream) {
  const float* coords = (const float*)d_in[0];
  const float* noise  = (const float*)d_in[1];
  const float* px     = (const float*)d_in[2];
  const float* py     = (const float*)d_in[3];
  const float* pz     = (const float*)d_in[4];
  const float* conv_w = (const float*)d_in[5];
  // conv_b (d_in[6]) unused: bias cancels exactly under batch-stat BN
  const float* gamma  = (const float*)d_in[7];
  const float* beta   = (const float*)d_in[8];
  float* out = (float*)d_out;
  float* ws = (float*)d_ws;
  __half* planes = (__half*)(ws + WS_PLANES_OFF);

  wprep_kernel<<<144, 256, 0, stream>>>(conv_w, ws);
  transpose_kernel<<<dim3(4, 256, 3), 256, 0, stream>>>(px, py, pz, ws);
  conv_mfma_kernel<<<dim3(2, 128, 3), 256, 0, stream>>>(ws, ws);
  stats_kernel<<<192, 256, 0, stream>>>(ws);
  finalize_kernel<<<1, 256, 0, stream>>>(gamma, beta, ws);
  apply_kernel<<<1536, 256, 0, stream>>>(ws, planes);
  sample_kernel<<<15625, 256, 0, stream>>>(coords, noise, planes, out);
}

// Round 4
// 366.491 us; speedup vs baseline: 1.0183x; 1.0046x over previous
//
#include <hip/hip_runtime.h>
#include <hip/hip_fp16.h>

#define N_POINTS 500000
#define BN_EPS 1e-5f
#define A_COEF -0.75f

typedef __attribute__((ext_vector_type(8))) short short8;
typedef __attribute__((ext_vector_type(4))) float floatx4;
typedef unsigned short ushort_t;
typedef unsigned int uint_t;

// -------- workspace layout (float offsets) --------
#define WS_WBF_OFF    0                          // bf16 weights [tap(9)][oc(64)][ic(64)]   : 18432 floats
#define WS_CONV_OFF   18432                      // conv HWC fp32 [3][128][128][64]          : 3145728
#define WS_SUM_OFF    (WS_CONV_OFF + 3145728)    // [3][64]                                  : 192
#define WS_SUMSQ_OFF  (WS_SUM_OFF + 192)
#define WS_SCALE_OFF  (WS_SUMSQ_OFF + 192)
#define WS_SHIFT_OFF  (WS_SCALE_OFF + 192)
#define WS_PLANES_OFF (WS_SHIFT_OFF + 192)       // fp16 planes HWC [3][128][128][64]        : 1572864 floats
#define WS_INBF_OFF   (WS_PLANES_OFF + 1572864)  // bf16 input HWC [3][256][256][64]         : 6291456 floats
// total ~44.1 MB

__device__ __forceinline__ ushort_t f2bf(float f) {
  uint_t u = __float_as_uint(f);
  uint_t r = (u + 0x7fffu + ((u >> 16) & 1u)) >> 16;
  return (ushort_t)r;
}
__device__ __forceinline__ float bf2f(ushort_t u) {
  return __uint_as_float(((uint_t)u) << 16);
}

// ================= prep: weights [oc][ic][3][3] fp32 -> [tap][oc][ic] bf16; zero stat accums
__global__ __launch_bounds__(256) void wprep_kernel(const float* __restrict__ w_in,
                                                    float* __restrict__ ws) {
  int i = blockIdx.x * 256 + threadIdx.x;  // < 36864
  if (i < 36864) {
    int ic = i & 63;
    int oc = (i >> 6) & 63;
    int kk = i >> 12;  // 0..8
    ((ushort_t*)(ws + WS_WBF_OFF))[i] = f2bf(w_in[(oc * 64 + ic) * 9 + kk]);
  }
  if (i < 384) ws[WS_SUM_OFF + i] = 0.0f;  // sums + sumsq contiguous
}

// ================= transpose: input CHW fp32 -> HWC bf16
// grid (4, 256, 3): x-tile, row y, plane
__global__ __launch_bounds__(256) void transpose_kernel(const float* __restrict__ p0,
                                                        const float* __restrict__ p1,
                                                        const float* __restrict__ p2,
                                                        float* __restrict__ ws) {
  __shared__ float tile[64][65];
  const int xt = blockIdx.x, y = blockIdx.y, pl = blockIdx.z;
  const float* src = (pl == 0) ? p0 : ((pl == 1) ? p1 : p2);
  ushort_t* dst = (ushort_t*)(ws + WS_INBF_OFF) + pl * (256 * 256 * 64);
  const int t = threadIdx.x;
  const int x0 = xt * 64;
  for (int i = t; i < 4096; i += 256) {
    int c = i >> 6, x = i & 63;
    tile[x][c] = src[(c * 256 + y) * 256 + x0 + x];
  }
  __syncthreads();
  uint_t* du = (uint_t*)dst;
  for (int i = t; i < 2048; i += 256) {
    int x = i >> 5, cp = (i & 31) * 2;
    uint_t lo = f2bf(tile[x][cp]);
    uint_t hi = f2bf(tile[x][cp + 1]);
    du[((y * 256 + x0 + x) * 64 + cp) >> 1] = (hi << 16) | lo;
  }
}

// ================= conv3x3 stride2 pad1 via MFMA bf16 (bias dropped: cancels in batch-stat BN)
// grid (2, 128, 3). 4 waves; wave computes 16 px x 64 oc. A from global HWC bf16, B from bf16 weights.
__global__ __launch_bounds__(256) void conv_mfma_kernel(const float* __restrict__ ws_r,
                                                        float* __restrict__ ws) {
  const int xh = blockIdx.x, oy = blockIdx.y, pz = blockIdx.z;
  const int t = threadIdx.x;
  const int wv = t >> 6, lane = t & 63;
  const int mn = lane & 15;   // A: px row m ; B: oc col n
  const int kg = lane >> 4;   // k-group (k = kg*8 + j)
  const int x0w = xh * 64 + wv * 16;

  const ushort_t* inb = (const ushort_t*)(ws_r + WS_INBF_OFF) + pz * (256 * 256 * 64);
  const ushort_t* wbf = (const ushort_t*)(ws_r + WS_WBF_OFF);

  floatx4 acc[4] = {{0.f,0.f,0.f,0.f},{0.f,0.f,0.f,0.f},{0.f,0.f,0.f,0.f},{0.f,0.f,0.f,0.f}};

  for (int ky = 0; ky < 3; ky++) {
    int y = 2 * oy - 1 + ky;
    if (y < 0) continue;  // y <= 255 always
    const ushort_t* rowp = inb + y * (256 * 64);
    for (int kx = 0; kx < 3; kx++) {
      int xm = 2 * (x0w + mn) - 1 + kx;     // only -1 can be OOB (max 255)
      bool vx = xm >= 0;
      int xc = vx ? xm : 0;
      const ushort_t* abase = rowp + xc * 64 + kg * 8;
      const ushort_t* wbase = wbf + ((ky * 3 + kx) * 64 + mn) * 64 + kg * 8;
#pragma unroll
      for (int kc = 0; kc < 2; kc++) {
        union { int4 i4; short8 s8; } au;
        au.i4 = *reinterpret_cast<const int4*>(abase + kc * 32);
        if (!vx) au.i4 = make_int4(0, 0, 0, 0);
#pragma unroll
        for (int nt = 0; nt < 4; nt++) {
          union { int4 i4; short8 s8; } bu;
          bu.i4 = *reinterpret_cast<const int4*>(wbase + nt * 1024 + kc * 32);
          acc[nt] = __builtin_amdgcn_mfma_f32_16x16x32_bf16(au.s8, bu.s8, acc[nt], 0, 0, 0);
        }
      }
    }
  }
  // D: col(oc) = lane&15, row(px) = (lane>>4)*4 + reg
  float* cout = ws + WS_CONV_OFF + ((pz * 128 + oy) * 128 + x0w) * 64;
#pragma unroll
  for (int nt = 0; nt < 4; nt++) {
#pragma unroll
    for (int r = 0; r < 4; r++) {
      cout[(kg * 4 + r) * 64 + nt * 16 + mn] = acc[nt][r];
    }
  }
}

// ================= BN stats: per (plane, channel) sum & sumsq over 16384 px
__global__ __launch_bounds__(256) void stats_kernel(float* __restrict__ ws) {
  const int b = blockIdx.x;
  const int plane = b >> 6, chunk = b & 63;
  const int t = threadIdx.x;
  const int c = t & 63, g = t >> 6;
  const float* base = ws + WS_CONV_OFF + plane * (16384 * 64);
  float s = 0.0f, s2 = 0.0f;
  const int row0 = chunk * 256 + g * 64;
  for (int i = 0; i < 64; i++) {
    float v = base[(row0 + i) * 64 + c];
    s += v;
    s2 = fmaf(v, v, s2);
  }
  __shared__ float rs[256], rs2[256];
  rs[t] = s; rs2[t] = s2;
  __syncthreads();
  if (t < 64) {
    s = rs[t] + rs[t + 64] + rs[t + 128] + rs[t + 192];
    s2 = rs2[t] + rs2[t + 64] + rs2[t + 128] + rs2[t + 192];
    atomicAdd(&ws[WS_SUM_OFF + plane * 64 + c], s);
    atomicAdd(&ws[WS_SUMSQ_OFF + plane * 64 + c], s2);
  }
}

__global__ void finalize_kernel(const float* __restrict__ gamma,
                                const float* __restrict__ beta,
                                float* __restrict__ ws) {
  int i = threadIdx.x;
  if (i < 192) {
    int c = i & 63;
    float mu = ws[WS_SUM_OFF + i] * (1.0f / 16384.0f);
    float var = ws[WS_SUMSQ_OFF + i] * (1.0f / 16384.0f) - mu * mu;
    var = fmaxf(var, 0.0f);
    float rstd = 1.0f / sqrtf(var + BN_EPS);
    float sc = gamma[c] * rstd;
    ws[WS_SCALE_OFF + i] = sc;
    ws[WS_SHIFT_OFF + i] = beta[c] - mu * sc;
  }
}

// ================= apply BN + relu + fused avgpool(3x3 s2 p1, count_include_pad) + pack fp16
// thread = (plane, px, 8-channel group); 393216 threads
__global__ __launch_bounds__(256) void apply_kernel(float* __restrict__ ws,
                                                    __half* __restrict__ planes) {
  int idx = blockIdx.x * 256 + threadIdx.x;  // < 393216
  int g = idx & 7;
  int p = (idx >> 3) & 16383;
  int pl = idx >> 17;
  int oy = p >> 7, ox = p & 127;
  int cb = g * 8;

  const float* conv = ws + WS_CONV_OFF;
  float4 a0 = *reinterpret_cast<const float4*>(conv + (size_t)idx * 8);
  float4 a1 = *reinterpret_cast<const float4*>(conv + (size_t)idx * 8 + 4);

  float sc[8], sh[8];
#pragma unroll
  for (int k = 0; k < 8; k++) {
    sc[k] = ws[WS_SCALE_OFF + pl * 64 + cb + k];
    sh[k] = ws[WS_SHIFT_OFF + pl * 64 + cb + k];
  }

  const ushort_t* inb = (const ushort_t*)(ws + WS_INBF_OFF) + pl * (256 * 256 * 64);
  float ps[8];
#pragma unroll
  for (int k = 0; k < 8; k++) ps[k] = 0.0f;
#pragma unroll
  for (int r = 0; r < 3; r++) {
    int yy = 2 * oy - 1 + r;
    if (yy < 0) continue;  // <= 255 always
#pragma unroll
    for (int s = 0; s < 3; s++) {
      int xx = 2 * ox - 1 + s;
      if (xx < 0) continue;
      union { int4 i4; ushort_t u[8]; } ub;
      ub.i4 = *reinterpret_cast<const int4*>(inb + (yy * 256 + xx) * 64 + cb);
#pragma unroll
      for (int k = 0; k < 8; k++) ps[k] += bf2f(ub.u[k]);
    }
  }

  float v[8] = {a0.x, a0.y, a0.z, a0.w, a1.x, a1.y, a1.z, a1.w};
  union { int4 i4; __half h[8]; } ob;
#pragma unroll
  for (int k = 0; k < 8; k++) {
    float r = fmaxf(fmaf(v[k], sc[k], sh[k]), 0.0f) + ps[k] * (1.0f / 9.0f);
    ob.h[k] = __float2half(r);
  }
  *reinterpret_cast<int4*>(planes + (size_t)idx * 8) = ob.i4;
}

// ================= bicubic sampling, 3 planes fused
__device__ __forceinline__ void cubic_w(float t, float w[4]) {
  float t1 = t + 1.0f;
  w[0] = ((A_COEF * t1 - 5.0f * A_COEF) * t1 + 8.0f * A_COEF) * t1 - 4.0f * A_COEF;
  w[1] = ((A_COEF + 2.0f) * t - (A_COEF + 3.0f)) * t * t + 1.0f;
  float s = 1.0f - t;
  w[2] = ((A_COEF + 2.0f) * s - (A_COEF + 3.0f)) * s * s + 1.0f;
  w[3] = 1.0f - w[0] - w[1] - w[2];
}

// One tap = one asm block: 8x v_fma_mix_f32 (fpext(f16)*w + acc, exact fma-f32
// numerics). Single block keeps the 8 accumulators pinned in place across all
// 48 taps -> no inter-asm v_mov glue.
__device__ __forceinline__ void fma_mix_tap(float& a0, float& a1, float& a2, float& a3,
                                            float& a4, float& a5, float& a6, float& a7,
                                            uint4 q, float w) {
  asm("v_fma_mix_f32 %0, %8, %12, %0 op_sel:[0,0,0] op_sel_hi:[1,0,0]\n\t"
      "v_fma_mix_f32 %1, %8, %12, %1 op_sel:[1,0,0] op_sel_hi:[1,0,0]\n\t"
      "v_fma_mix_f32 %2, %9, %12, %2 op_sel:[0,0,0] op_sel_hi:[1,0,0]\n\t"
      "v_fma_mix_f32 %3, %9, %12, %3 op_sel:[1,0,0] op_sel_hi:[1,0,0]\n\t"
      "v_fma_mix_f32 %4, %10, %12, %4 op_sel:[0,0,0] op_sel_hi:[1,0,0]\n\t"
      "v_fma_mix_f32 %5, %10, %12, %5 op_sel:[1,0,0] op_sel_hi:[1,0,0]\n\t"
      "v_fma_mix_f32 %6, %11, %12, %6 op_sel:[0,0,0] op_sel_hi:[1,0,0]\n\t"
      "v_fma_mix_f32 %7, %11, %12, %7 op_sel:[1,0,0] op_sel_hi:[1,0,0]"
      : "+v"(a0), "+v"(a1), "+v"(a2), "+v"(a3),
        "+v"(a4), "+v"(a5), "+v"(a6), "+v"(a7)
      : "v"(q.x), "v"(q.y), "v"(q.z), "v"(q.w), "v"(w));
}

// group of 8 lanes = one point; lane l handles channels [l*8, l*8+8).
// v4: per-tap asm block (no mov glue), sched_barrier-enforced 16-tap preload
//     per plane (16 outstanding dwordx4), uniform-base + 32-bit voffset.
__global__ __launch_bounds__(256) void sample_kernel(const float* __restrict__ coords,
                                                     const float* __restrict__ noise,
                                                     const __half* __restrict__ planes,
                                                     float* __restrict__ out) {
  const int t = threadIdx.x;
  const int wv = t >> 6, lane = t & 63;
  const int g = lane >> 3, l = lane & 7;
  const int n = blockIdx.x * 32 + wv * 8 + g;

  const float c0 = (coords[n * 3 + 0] + 1.0f) * 0.5f;
  const float c1 = (coords[n * 3 + 1] + 1.0f) * 0.5f;
  const float c2 = (coords[n * 3 + 2] + 1.0f) * 0.5f;

  float a0 = 0.f, a1 = 0.f, a2 = 0.f, a3 = 0.f;
  float a4 = 0.f, a5 = 0.f, a6 = 0.f, a7 = 0.f;

#pragma unroll
  for (int p = 0; p < 3; p++) {
    float u = (p == 1) ? c1 : c0;   // p0:(c0,c1) p1:(c1,c2) p2:(c0,c2)
    float v = (p == 0) ? c1 : c2;
    u += noise[(p * N_POINTS + n) * 2 + 0];
    v += noise[(p * N_POINTS + n) * 2 + 1];
    float gx = fminf(fmaxf(fmaf(u, 63.5f, 63.5f), 0.0f), 127.0f);
    float gy = fminf(fmaxf(fmaf(v, 63.5f, 63.5f), 0.0f), 127.0f);
    float x0f = floorf(gx), y0f = floorf(gy);
    float tx = gx - x0f, ty = gy - y0f;
    int ix = (int)x0f, iy = (int)y0f;
    float wx[4], wy[4];
    cubic_w(tx, wx);
    cubic_w(ty, wy);

    // 32-bit element offsets from the uniform plane base (SGPR base + voffset)
    const int rb = p * (128 * 128 * 64) + l * 8;
    int ro[4], xo[4];
#pragma unroll
    for (int i = 0; i < 4; i++) ro[i] = rb + min(max(iy - 1 + i, 0), 127) * (128 * 64);
#pragma unroll
    for (int j = 0; j < 4; j++) xo[j] = min(max(ix - 1 + j, 0), 127) * 64;

    // issue all 16 tap loads; sched_barrier stops the scheduler from sinking
    // them into the consume chain (keeps ~16 outstanding)
    uint4 q[16];
#pragma unroll
    for (int i = 0; i < 4; i++) {
#pragma unroll
      for (int j = 0; j < 4; j++) {
        q[i * 4 + j] = *reinterpret_cast<const uint4*>(planes + ro[i] + xo[j]);
      }
    }
    __builtin_amdgcn_sched_barrier(0);

#pragma unroll
    for (int i = 0; i < 4; i++) {
#pragma unroll
      for (int j = 0; j < 4; j++) {
        float w = wy[i] * wx[j];
        fma_mix_tap(a0, a1, a2, a3, a4, a5, a6, a7, q[i * 4 + j], w);
      }
    }
  }

  float* op = out + (size_t)n * 64 + l * 8;
  *reinterpret_cast<float4*>(op)     = make_float4(a0, a1, a2, a3);
  *reinterpret_cast<float4*>(op + 4) = make_float4(a4, a5, a6, a7);
}

extern "C" void kernel_launch(void* const* d_in, const int* in_sizes, int n_in,
                              void* d_out, int out_size, void* d_ws, size_t ws_size,
                              hipStream_t stream) {
  const float* coords = (const float*)d_in[0];
  const float* noise  = (const float*)d_in[1];
  const float* px     = (const float*)d_in[2];
  const float* py     = (const float*)d_in[3];
  const float* pz     = (const float*)d_in[4];
  const float* conv_w = (const float*)d_in[5];
  // conv_b (d_in[6]) unused: bias cancels exactly under batch-stat BN
  const float* gamma  = (const float*)d_in[7];
  const float* beta   = (const float*)d_in[8];
  float* out = (float*)d_out;
  float* ws = (float*)d_ws;
  __half* planes = (__half*)(ws + WS_PLANES_OFF);

  wprep_kernel<<<144, 256, 0, stream>>>(conv_w, ws);
  transpose_kernel<<<dim3(4, 256, 3), 256, 0, stream>>>(px, py, pz, ws);
  conv_mfma_kernel<<<dim3(2, 128, 3), 256, 0, stream>>>(ws, ws);
  stats_kernel<<<192, 256, 0, stream>>>(ws);
  finalize_kernel<<<1, 256, 0, stream>>>(gamma, beta, ws);
  apply_kernel<<<1536, 256, 0, stream>>>(ws, planes);
  sample_kernel<<<15625, 256, 0, stream>>>(coords, noise, planes, out);
}